// Round 1
// baseline (341.287 us; speedup 1.0000x reference)
//
#include <hip/hip_runtime.h>
#include <cstdint>
#include <cstddef>

#define NP  1024
#define FD  10
#define NV  4
#define BSZ 128

// One direction of the Chamfer match.
// Rows: each thread owns rows n = tid + 256*r (r=0..3). For each row, scan all
// 1024 columns (wave-uniform LDS reads -> broadcast), track min sqdist + argmin,
// then accumulate the xy L2 distance (or 1.0 if min sqdist > 6.0).
__device__ __forceinline__ float dir_pass(
    int tid,
    const float4* __restrict__ rvis, const float* __restrict__ rss, const float2* __restrict__ rxy,
    const float4* __restrict__ cvis, const float* __restrict__ css, const float2* __restrict__ cxy)
{
    float4 rv[4];
    float  rs[4];
    float  bestd[4];
    int    bidx[4];
#pragma unroll
    for (int r = 0; r < 4; ++r) {
        int n = tid + 256 * r;
        rv[r] = rvis[n];
        rs[r] = rss[n];
        bestd[r] = 3.0e38f;
        bidx[r]  = 0;
    }

    for (int m = 0; m < NP; ++m) {
        float4 c  = cvis[m];   // uniform address across wave -> LDS broadcast
        float  cs = css[m];
#pragma unroll
        for (int r = 0; r < 4; ++r) {
            float t = rv[r].x * c.x;
            t = fmaf(rv[r].y, c.y, t);
            t = fmaf(rv[r].z, c.z, t);
            t = fmaf(rv[r].w, c.w, t);
            float d = fmaf(-2.0f, t, rs[r] + cs);   // ||s-g||^2 = ss + gg - 2 s.g
            bool lt = d < bestd[r];                 // strict < keeps first index on ties (matches jnp.argmin)
            bestd[r] = fminf(bestd[r], d);
            bidx[r]  = lt ? m : bidx[r];
        }
    }

    float sum = 0.0f;
#pragma unroll
    for (int r = 0; r < 4; ++r) {
        int n = tid + 256 * r;
        float2 a = rxy[n];
        float2 b = cxy[bidx[r]];
        float dx = a.x - b.x;
        float dy = a.y - b.y;
        float dist = sqrtf(dx * dx + dy * dy);
        if (bestd[r] > 6.0f) dist = 1.0f;   // LATENT_DIST_THRESHOLD
        sum += dist;
    }
    return sum;
}

extern "C" __global__ __launch_bounds__(256, 2)
void chamfer_pairs(const float* __restrict__ ag, const float* __restrict__ dg,
                   const float* __restrict__ nmean, const float* __restrict__ nstd,
                   float* __restrict__ partial /* [BSZ*NV] */)
{
    __shared__ float4 svis[NP];
    __shared__ float4 gvis[NP];
    __shared__ float  sss[NP];
    __shared__ float  ggg[NP];
    __shared__ float2 sxy[NP];
    __shared__ float2 gxy[NP];
    __shared__ float  cmean[FD];
    __shared__ float  cstd[FD];
    __shared__ float  redbuf[4];

    const int tid  = threadIdx.x;
    const int pair = blockIdx.x;              // b * NV + view
    const float* A = ag + (size_t)pair * (NP * FD);
    const float* G = dg + (size_t)pair * (NP * FD);

    if (tid < FD) { cmean[tid] = nmean[tid]; cstd[tid] = nstd[tid]; }
    __syncthreads();

    // Coalesced staging: normalize, keep xy (f=0,1) and vis (f=5..8).
    for (int idx = tid; idx < NP * FD; idx += 256) {
        int n = idx / FD;
        int f = idx - n * FD;
        float va = fmaf(A[idx], cstd[f], cmean[f]);
        float vg = fmaf(G[idx], cstd[f], cmean[f]);
        if (f < 2) {
            ((float*)&sxy[n])[f] = va;
            ((float*)&gxy[n])[f] = vg;
        } else if (f >= 5 && f < 9) {
            ((float*)&svis[n])[f - 5] = va;
            ((float*)&gvis[n])[f - 5] = vg;
        }
    }
    __syncthreads();

    for (int n = tid; n < NP; n += 256) {
        float4 v = svis[n];
        sss[n] = v.x * v.x + v.y * v.y + v.z * v.z + v.w * v.w;
        float4 w = gvis[n];
        ggg[n] = w.x * w.x + w.y * w.y + w.z * w.z + w.w * w.w;
    }
    __syncthreads();

    // Direction A: rows = state (min over goals)  -> sum of xy_dist_2
    // Direction B: rows = goal  (min over states) -> sum of xy_dist_1
    float sum = dir_pass(tid, svis, sss, sxy, gvis, ggg, gxy)
              + dir_pass(tid, gvis, ggg, gxy, svis, sss, sxy);

    // Block reduction: wave shuffle then LDS across the 4 waves.
    for (int o = 32; o > 0; o >>= 1) sum += __shfl_down(sum, o, 64);
    if ((tid & 63) == 0) redbuf[tid >> 6] = sum;
    __syncthreads();
    if (tid == 0) {
        float s = redbuf[0] + redbuf[1] + redbuf[2] + redbuf[3];
        // rv = (reward_g2s + reward_s2g)/2 = -(sumA + sumB) / (2*1024)
        partial[pair] = s * (-1.0f / 2048.0f);
    }
}

extern "C" __global__ void chamfer_final(const float* __restrict__ partial,
                                         float* __restrict__ out)
{
    int b = threadIdx.x;
    if (b < BSZ) {
        float s = partial[NV * b + 0] + partial[NV * b + 1]
                + partial[NV * b + 2] + partial[NV * b + 3];
        out[b] = s * 0.25f;   // mean over views, REWARD_SCALE = 1.0
    }
}

extern "C" void kernel_launch(void* const* d_in, const int* in_sizes, int n_in,
                              void* d_out, int out_size, void* d_ws, size_t ws_size,
                              hipStream_t stream)
{
    const float* ag = (const float*)d_in[0];   // achieved_goal (128,4,1024,10)
    const float* dg = (const float*)d_in[1];   // desired_goal  (128,4,1024,10)
    const float* nm = (const float*)d_in[2];   // norm_mean (10,)
    const float* ns = (const float*)d_in[3];   // norm_std  (10,)
    float* partial  = (float*)d_ws;            // [512] per-(b,view) rewards

    chamfer_pairs<<<BSZ * NV, 256, 0, stream>>>(ag, dg, nm, ns, partial);
    chamfer_final<<<1, BSZ, 0, stream>>>(partial, (float*)d_out);
}

// Round 2
// 280.254 us; speedup vs baseline: 1.2178x; 1.2178x over previous
//
#include <hip/hip_runtime.h>
#include <cstdint>
#include <cstddef>

#define NP  1024
#define FD  10
#define NV  4
#define BSZ 128
#define TPB 512   // threads per block; 8 waves; LDS 56KB -> 2 blocks/CU -> 16 waves/CU

// One direction of the Chamfer match. Each thread owns 2 rows (n = tid, tid+512).
// Inner loop is shift-reduced: argmin_m [ rs + cs_m - 2 r.c_m ] == argmin_m [ cs_m + r . c2_m ]
// where c2 = -2*c is prestored in LDS, so each entry costs 4 fma + cmp + min + cndmask.
__device__ __forceinline__ float dir_pass(
    int tid,
    const float4* __restrict__ rvis2, const float* __restrict__ rss, const float2* __restrict__ rxy,
    const float4* __restrict__ cvis2, const float* __restrict__ css, const float2* __restrict__ cxy)
{
    float4 rv[2];
    float  rthr[2];   // threshold test: (rs + bestd') > 6.0  <=>  bestd' > 6.0 - rs
    float  bestd[2];
    int    bidx[2];
#pragma unroll
    for (int r = 0; r < 2; ++r) {
        int n = tid + TPB * r;
        float4 t = rvis2[n];                       // stored as -2*vis; unscale for row use
        rv[r] = make_float4(-0.5f * t.x, -0.5f * t.y, -0.5f * t.z, -0.5f * t.w);
        rthr[r] = 6.0f - rss[n];
        bestd[r] = 3.0e38f;
        bidx[r]  = 0;
    }

    for (int m = 0; m < NP; m += 4) {
        // Wave-uniform LDS reads -> broadcast, near-free on the LDS pipe.
        float4 cs4 = *(const float4*)(css + m);
        float4 c0 = cvis2[m + 0];
        float4 c1 = cvis2[m + 1];
        float4 c2 = cvis2[m + 2];
        float4 c3 = cvis2[m + 3];
#pragma unroll
        for (int r = 0; r < 2; ++r) {
            float d0 = fmaf(rv[r].x, c0.x, cs4.x);
            d0 = fmaf(rv[r].y, c0.y, d0);
            d0 = fmaf(rv[r].z, c0.z, d0);
            d0 = fmaf(rv[r].w, c0.w, d0);
            float d1 = fmaf(rv[r].x, c1.x, cs4.y);
            d1 = fmaf(rv[r].y, c1.y, d1);
            d1 = fmaf(rv[r].z, c1.z, d1);
            d1 = fmaf(rv[r].w, c1.w, d1);
            float d2 = fmaf(rv[r].x, c2.x, cs4.z);
            d2 = fmaf(rv[r].y, c2.y, d2);
            d2 = fmaf(rv[r].z, c2.z, d2);
            d2 = fmaf(rv[r].w, c2.w, d2);
            float d3 = fmaf(rv[r].x, c3.x, cs4.w);
            d3 = fmaf(rv[r].y, c3.y, d3);
            d3 = fmaf(rv[r].z, c3.z, d3);
            d3 = fmaf(rv[r].w, c3.w, d3);
            // Ascending m with strict < keeps the FIRST index on ties (matches jnp.argmin).
            bool l0 = d0 < bestd[r]; bestd[r] = fminf(bestd[r], d0); bidx[r] = l0 ? (m + 0) : bidx[r];
            bool l1 = d1 < bestd[r]; bestd[r] = fminf(bestd[r], d1); bidx[r] = l1 ? (m + 1) : bidx[r];
            bool l2 = d2 < bestd[r]; bestd[r] = fminf(bestd[r], d2); bidx[r] = l2 ? (m + 2) : bidx[r];
            bool l3 = d3 < bestd[r]; bestd[r] = fminf(bestd[r], d3); bidx[r] = l3 ? (m + 3) : bidx[r];
        }
    }

    float sum = 0.0f;
#pragma unroll
    for (int r = 0; r < 2; ++r) {
        int n = tid + TPB * r;
        float2 a = rxy[n];
        float2 b = cxy[bidx[r]];
        float dx = a.x - b.x;
        float dy = a.y - b.y;
        float dist = sqrtf(dx * dx + dy * dy);
        if (bestd[r] > rthr[r]) dist = 1.0f;   // min_d > LATENT_DIST_THRESHOLD
        sum += dist;
    }
    return sum;
}

extern "C" __global__ __launch_bounds__(TPB, 4)
void chamfer_pairs(const float* __restrict__ ag, const float* __restrict__ dg,
                   const float* __restrict__ nmean, const float* __restrict__ nstd,
                   float* __restrict__ partial /* [BSZ*NV] */)
{
    __shared__ float4 svis2[NP];   // -2 * normalized vis (state)
    __shared__ float4 gvis2[NP];   // -2 * normalized vis (goal)
    __shared__ float  sss[NP];     // ||state vis||^2 (unscaled)
    __shared__ float  ggg[NP];     // ||goal vis||^2
    __shared__ float2 sxy[NP];
    __shared__ float2 gxy[NP];
    __shared__ float  sc[FD];      // per-feature scale (std, or -2*std for vis)
    __shared__ float  sh[FD];      // per-feature shift (mean, or -2*mean for vis)
    __shared__ float  redbuf[TPB / 64];

    const int tid  = threadIdx.x;
    const int pair = blockIdx.x;              // b * NV + view
    const float* A = ag + (size_t)pair * (NP * FD);
    const float* G = dg + (size_t)pair * (NP * FD);

    if (tid < FD) {
        bool vis = (tid >= 5 && tid < 9);
        float k = vis ? -2.0f : 1.0f;
        sc[tid] = k * nstd[tid];
        sh[tid] = k * nmean[tid];
    }
    __syncthreads();

    // Coalesced staging: normalize, keep xy (f=0,1) and vis (f=5..8, prescaled by -2).
    for (int idx = tid; idx < NP * FD; idx += TPB) {
        int n = idx / FD;
        int f = idx - n * FD;
        float va = fmaf(A[idx], sc[f], sh[f]);
        float vg = fmaf(G[idx], sc[f], sh[f]);
        if (f < 2) {
            ((float*)&sxy[n])[f] = va;
            ((float*)&gxy[n])[f] = vg;
        } else if (f >= 5 && f < 9) {
            ((float*)&svis2[n])[f - 5] = va;
            ((float*)&gvis2[n])[f - 5] = vg;
        }
    }
    __syncthreads();

    for (int n = tid; n < NP; n += TPB) {
        float4 v = svis2[n];   // = -2*vis  ->  ||vis||^2 = 0.25 * dot
        sss[n] = 0.25f * (v.x * v.x + v.y * v.y + v.z * v.z + v.w * v.w);
        float4 w = gvis2[n];
        ggg[n] = 0.25f * (w.x * w.x + w.y * w.y + w.z * w.z + w.w * w.w);
    }
    __syncthreads();

    // Direction A: rows = state (min over goals); Direction B: rows = goal.
    float sum = dir_pass(tid, svis2, sss, sxy, gvis2, ggg, gxy)
              + dir_pass(tid, gvis2, ggg, gxy, svis2, sss, sxy);

    // Block reduction: wave shuffle then LDS across the 8 waves.
    for (int o = 32; o > 0; o >>= 1) sum += __shfl_down(sum, o, 64);
    if ((tid & 63) == 0) redbuf[tid >> 6] = sum;
    __syncthreads();
    if (tid == 0) {
        float s = 0.0f;
#pragma unroll
        for (int w = 0; w < TPB / 64; ++w) s += redbuf[w];
        // rv = (reward_g2s + reward_s2g)/2 = -(sumA + sumB) / (2*1024)
        partial[pair] = s * (-1.0f / 2048.0f);
    }
}

extern "C" __global__ void chamfer_final(const float* __restrict__ partial,
                                         float* __restrict__ out)
{
    int b = threadIdx.x;
    if (b < BSZ) {
        float s = partial[NV * b + 0] + partial[NV * b + 1]
                + partial[NV * b + 2] + partial[NV * b + 3];
        out[b] = s * 0.25f;   // mean over views, REWARD_SCALE = 1.0
    }
}

extern "C" void kernel_launch(void* const* d_in, const int* in_sizes, int n_in,
                              void* d_out, int out_size, void* d_ws, size_t ws_size,
                              hipStream_t stream)
{
    const float* ag = (const float*)d_in[0];   // achieved_goal (128,4,1024,10)
    const float* dg = (const float*)d_in[1];   // desired_goal  (128,4,1024,10)
    const float* nm = (const float*)d_in[2];   // norm_mean (10,)
    const float* ns = (const float*)d_in[3];   // norm_std  (10,)
    float* partial  = (float*)d_ws;            // [512] per-(b,view) rewards

    chamfer_pairs<<<BSZ * NV, TPB, 0, stream>>>(ag, dg, nm, ns, partial);
    chamfer_final<<<1, BSZ, 0, stream>>>(partial, (float*)d_out);
}

// Round 3
// 212.208 us; speedup vs baseline: 1.6083x; 1.3207x over previous
//
#include <hip/hip_runtime.h>
#include <cstdint>
#include <cstddef>

#define NP  1024
#define FD  10
#define NV  4
#define BSZ 128
#define TPB 256
#define RPT 4    // rows per thread: column LDS loads amortize over 4 rows

// One direction of the Chamfer match. Each thread owns 4 rows (n = tid + 256*r).
// Shift-reduced distance: argmin_m [rs + cs_m - 2 r.c_m] == argmin_m [cs_m + r.c2_m],
// c2 = -2*c prestored in LDS. Inner loop processes 8 columns/iter with a min3
// tree (block-min) and tracks only the winning BLOCK; the exact first-tie index
// inside the block is recovered in the epilogue by replaying the identical fmaf
// chain on the same LDS values (bit-exact).
__device__ __forceinline__ float dir_pass(
    int tid,
    const float4* rvis2, const float* rss,
    const float4* cvis2, const float* css,
    const float* __restrict__ rxyg,   // global row particles (this pair), stride FD
    const float* __restrict__ cxyg,   // global col particles (this pair), stride FD
    float std0, float mean0, float std1, float mean1)
{
    float4 rv[RPT];
    float  rthr[RPT];    // (rs + bestd') > 6  <=>  bestd' > 6 - rs
    float  bestd[RPT];
    int    bblk[RPT];
#pragma unroll
    for (int r = 0; r < RPT; ++r) {
        int n = tid + TPB * r;
        float4 t = rvis2[n];                        // stored as -2*vis; unscale for row use
        rv[r] = make_float4(-0.5f * t.x, -0.5f * t.y, -0.5f * t.z, -0.5f * t.w);
        rthr[r] = 6.0f - rss[n];
        bestd[r] = 3.0e38f;
        bblk[r]  = 0;
    }

    for (int m = 0; m < NP; m += 8) {
        float4 c0 = cvis2[m + 0];
        float4 c1 = cvis2[m + 1];
        float4 c2 = cvis2[m + 2];
        float4 c3 = cvis2[m + 3];
        float4 c4 = cvis2[m + 4];
        float4 c5 = cvis2[m + 5];
        float4 c6 = cvis2[m + 6];
        float4 c7 = cvis2[m + 7];
        float4 csA = *(const float4*)(css + m);
        float4 csB = *(const float4*)(css + m + 4);
#pragma unroll
        for (int r = 0; r < RPT; ++r) {
            float4 v = rv[r];
            float d0 = fmaf(v.x, c0.x, csA.x); d0 = fmaf(v.y, c0.y, d0); d0 = fmaf(v.z, c0.z, d0); d0 = fmaf(v.w, c0.w, d0);
            float d1 = fmaf(v.x, c1.x, csA.y); d1 = fmaf(v.y, c1.y, d1); d1 = fmaf(v.z, c1.z, d1); d1 = fmaf(v.w, c1.w, d1);
            float d2 = fmaf(v.x, c2.x, csA.z); d2 = fmaf(v.y, c2.y, d2); d2 = fmaf(v.z, c2.z, d2); d2 = fmaf(v.w, c2.w, d2);
            float d3 = fmaf(v.x, c3.x, csA.w); d3 = fmaf(v.y, c3.y, d3); d3 = fmaf(v.z, c3.z, d3); d3 = fmaf(v.w, c3.w, d3);
            float d4 = fmaf(v.x, c4.x, csB.x); d4 = fmaf(v.y, c4.y, d4); d4 = fmaf(v.z, c4.z, d4); d4 = fmaf(v.w, c4.w, d4);
            float d5 = fmaf(v.x, c5.x, csB.y); d5 = fmaf(v.y, c5.y, d5); d5 = fmaf(v.z, c5.z, d5); d5 = fmaf(v.w, c5.w, d5);
            float d6 = fmaf(v.x, c6.x, csB.z); d6 = fmaf(v.y, c6.y, d6); d6 = fmaf(v.z, c6.z, d6); d6 = fmaf(v.w, c6.w, d6);
            float d7 = fmaf(v.x, c7.x, csB.w); d7 = fmaf(v.y, c7.y, d7); d7 = fmaf(v.z, c7.z, d7); d7 = fmaf(v.w, c7.w, d7);
            // block-min via v_min3 tree (min is exact & associative: no NaNs here)
            float p0 = fminf(fminf(d0, d1), d2);
            float p1 = fminf(fminf(d3, d4), d5);
            float p2 = fminf(d6, d7);
            float bm = fminf(fminf(p0, p1), p2);
            bool lt = bm < bestd[r];               // strict < keeps FIRST block on ties
            bestd[r] = fminf(bestd[r], bm);
            bblk[r]  = lt ? m : bblk[r];
        }
    }

    // Epilogue: replay the winning block to recover the exact first-tie index,
    // then gather xy from global (L2-resident) and accumulate the L2 distance.
    float sum = 0.0f;
#pragma unroll
    for (int r = 0; r < RPT; ++r) {
        int n  = tid + TPB * r;
        int mb = bblk[r];
        float4 v = rv[r];
        float4 csA = *(const float4*)(css + mb);
        float4 csB = *(const float4*)(css + mb + 4);
        float d[8];
        float cs[8] = {csA.x, csA.y, csA.z, csA.w, csB.x, csB.y, csB.z, csB.w};
#pragma unroll
        for (int j = 0; j < 8; ++j) {
            float4 c = cvis2[mb + j];
            float t = fmaf(v.x, c.x, cs[j]);
            t = fmaf(v.y, c.y, t);
            t = fmaf(v.z, c.z, t);
            t = fmaf(v.w, c.w, t);
            d[j] = t;
        }
        int sel = 0;
#pragma unroll
        for (int j = 7; j >= 0; --j)            // descending so the SMALLEST j wins
            if (d[j] == bestd[r]) sel = j;
        int idx = mb + sel;

        float gx = fmaf(cxyg[(size_t)idx * FD + 0], std0, mean0);
        float gy = fmaf(cxyg[(size_t)idx * FD + 1], std1, mean1);
        float ax = fmaf(rxyg[(size_t)n * FD + 0], std0, mean0);
        float ay = fmaf(rxyg[(size_t)n * FD + 1], std1, mean1);
        float dx = ax - gx;
        float dy = ay - gy;
        float dist = sqrtf(dx * dx + dy * dy);
        if (bestd[r] > rthr[r]) dist = 1.0f;    // min_d > LATENT_DIST_THRESHOLD
        sum += dist;
    }
    return sum;
}

extern "C" __global__ __launch_bounds__(TPB, 4)
void chamfer_pairs(const float* __restrict__ ag, const float* __restrict__ dg,
                   const float* __restrict__ nmean, const float* __restrict__ nstd,
                   float* __restrict__ partial /* [BSZ*NV] */)
{
    // Manual LDS layout: exactly 40960 B -> 4 blocks/CU (160 KiB / 40 KiB).
    __shared__ __align__(16) float smem[10240];
    float4* svis2 = (float4*)smem;            // [1024] -2*normalized state vis
    float4* gvis2 = (float4*)(smem + 4096);   // [1024] -2*normalized goal vis
    float*  sss   = smem + 8192;              // [1024] ||state vis||^2
    float*  ggg   = smem + 9216;              // [1024] ||goal vis||^2
    float*  scsh  = smem + 8192;              // alias (dead after staging): sc[10], sh[10]
    float*  redbuf= smem + 9216;              // alias onto ggg (dead after both passes)

    const int tid  = threadIdx.x;
    const int pair = blockIdx.x;              // b * NV + view
    const float* A = ag + (size_t)pair * (NP * FD);
    const float* G = dg + (size_t)pair * (NP * FD);

    if (tid < FD) {
        scsh[tid]      = -2.0f * nstd[tid];
        scsh[FD + tid] = -2.0f * nmean[tid];
    }
    __syncthreads();

    // Stage vis features (f=5..8) into LDS, prescaled by -2 and normalized.
    for (int idx = tid; idx < NP * FD; idx += TPB) {
        int n = idx / FD;
        int f = idx - n * FD;
        if (f >= 5 && f < 9) {
            float va = fmaf(A[idx], scsh[f], scsh[FD + f]);
            float vg = fmaf(G[idx], scsh[f], scsh[FD + f]);
            ((float*)&svis2[n])[f - 5] = va;
            ((float*)&gvis2[n])[f - 5] = vg;
        }
    }
    __syncthreads();

    // Squared norms (overwrites the scsh alias region -- scsh is dead now).
    for (int n = tid; n < NP; n += TPB) {
        float4 v = svis2[n];   // = -2*vis -> ||vis||^2 = 0.25 * dot(v,v)
        sss[n] = 0.25f * (v.x * v.x + v.y * v.y + v.z * v.z + v.w * v.w);
        float4 w = gvis2[n];
        ggg[n] = 0.25f * (w.x * w.x + w.y * w.y + w.z * w.z + w.w * w.w);
    }
    __syncthreads();

    const float std0 = nstd[0], mean0 = nmean[0];
    const float std1 = nstd[1], mean1 = nmean[1];

    // Direction A: rows = state (min over goals); Direction B: rows = goal.
    float sum = dir_pass(tid, svis2, sss, gvis2, ggg, A, G, std0, mean0, std1, mean1)
              + dir_pass(tid, gvis2, ggg, svis2, sss, G, A, std0, mean0, std1, mean1);

    // Wave shuffle reduce, then across the 4 waves via redbuf (aliases ggg;
    // barrier first so no wave still reads ggg).
    for (int o = 32; o > 0; o >>= 1) sum += __shfl_down(sum, o, 64);
    __syncthreads();
    if ((tid & 63) == 0) redbuf[tid >> 6] = sum;
    __syncthreads();
    if (tid == 0) {
        float s = redbuf[0] + redbuf[1] + redbuf[2] + redbuf[3];
        // rv = (reward_g2s + reward_s2g)/2 = -(sumA + sumB) / (2*1024)
        partial[pair] = s * (-1.0f / 2048.0f);
    }
}

extern "C" __global__ void chamfer_final(const float* __restrict__ partial,
                                         float* __restrict__ out)
{
    int b = threadIdx.x;
    if (b < BSZ) {
        float s = partial[NV * b + 0] + partial[NV * b + 1]
                + partial[NV * b + 2] + partial[NV * b + 3];
        out[b] = s * 0.25f;   // mean over views, REWARD_SCALE = 1.0
    }
}

extern "C" void kernel_launch(void* const* d_in, const int* in_sizes, int n_in,
                              void* d_out, int out_size, void* d_ws, size_t ws_size,
                              hipStream_t stream)
{
    const float* ag = (const float*)d_in[0];   // achieved_goal (128,4,1024,10)
    const float* dg = (const float*)d_in[1];   // desired_goal  (128,4,1024,10)
    const float* nm = (const float*)d_in[2];   // norm_mean (10,)
    const float* ns = (const float*)d_in[3];   // norm_std  (10,)
    float* partial  = (float*)d_ws;            // [512] per-(b,view) rewards

    chamfer_pairs<<<BSZ * NV, TPB, 0, stream>>>(ag, dg, nm, ns, partial);
    chamfer_final<<<1, BSZ, 0, stream>>>(partial, (float*)d_out);
}